// Round 4
// baseline (144.117 us; speedup 1.0000x reference)
//
#include <hip/hip_runtime.h>

#define N_TOK   16384
#define DMODEL  2048
#define N_EXP   16
#define CAP     2048             // 2 * N_TOK / N_EXP
#define CHUNK   64               // one wave per chunk
#define N_CHUNK (N_TOK / CHUNK)  // 256

// ---------------------------------------------------------------------------
// K1: fused routing. 256 blocks x 64 threads (1 wave each, all co-resident on
// 256 CUs -> lookback spin cannot deadlock).
//  - per-token argmax (first-max semantics) -> expert_f
//  - per-chunk expert histogram via ballots (lane ex holds count of expert ex)
//  - decoupled-lookback exclusive scan across chunks (device-scope atomics)
//  - in-chunk rank via ballot -> pos, keep, slot_map; block 255 writes count
// ---------------------------------------------------------------------------
__global__ void __launch_bounds__(64)
k_route(const float* __restrict__ score,
        float* __restrict__ expert_f,
        float* __restrict__ pos_f,
        float* __restrict__ keep_f,
        int* __restrict__ slot_map,
        int* __restrict__ count,
        int* __restrict__ agg,      // [N_CHUNK][N_EXP]
        int* __restrict__ incl,     // [N_CHUNK][N_EXP]
        int* __restrict__ flag) {   // [N_CHUNK], pre-zeroed each call
    const int lane = threadIdx.x;     // 0..63
    const int c    = blockIdx.x;      // chunk id
    const int t    = c * CHUNK + lane;

    // ---- argmax over 16 scores (strict > keeps first max) ----
    const float4* s4 = (const float4*)(score + (size_t)t * N_EXP);
    float4 a = s4[0], b = s4[1], cc = s4[2], d = s4[3];
    float v[16] = {a.x,a.y,a.z,a.w, b.x,b.y,b.z,b.w,
                   cc.x,cc.y,cc.z,cc.w, d.x,d.y,d.z,d.w};
    float best = v[0];
    int e = 0;
#pragma unroll
    for (int j = 1; j < 16; ++j)
        if (v[j] > best) { best = v[j]; e = j; }
    expert_f[t] = (float)e;

    // ---- per-chunk histogram + in-wave rank via ballots ----
    const unsigned long long below = (1ull << lane) - 1ull;
    int cnt = 0, rank = 0;
#pragma unroll
    for (int ex = 0; ex < N_EXP; ++ex) {
        unsigned long long m = __ballot(e == ex);
        if (e == ex) rank = __popcll(m & below);
        if (lane == ex) cnt = __popcll(m);   // lane ex owns expert ex
    }

    // ---- decoupled lookback: base = sum of hist over chunks < c ----
    int base = 0;                            // valid in lanes 0..15
    if (c == 0) {
        if (lane < N_EXP)
            __hip_atomic_store(&incl[lane], cnt, __ATOMIC_RELAXED,
                               __HIP_MEMORY_SCOPE_AGENT);
        __hip_atomic_store(&flag[0], 2, __ATOMIC_RELEASE,
                           __HIP_MEMORY_SCOPE_AGENT);
    } else {
        if (lane < N_EXP)
            __hip_atomic_store(&agg[c * N_EXP + lane], cnt, __ATOMIC_RELAXED,
                               __HIP_MEMORY_SCOPE_AGENT);
        __hip_atomic_store(&flag[c], 1, __ATOMIC_RELEASE,
                           __HIP_MEMORY_SCOPE_AGENT);
        int p = c - 1;
        for (;;) {
            int f = 0;
            if (lane == 0)
                f = __hip_atomic_load(&flag[p], __ATOMIC_ACQUIRE,
                                      __HIP_MEMORY_SCOPE_AGENT);
            f = __shfl(f, 0);
            if (f == 0) continue;            // predecessor not published yet
            if (lane < N_EXP) {
                const int* src = (f == 2) ? &incl[p * N_EXP + lane]
                                          : &agg[p * N_EXP + lane];
                base += __hip_atomic_load(src, __ATOMIC_RELAXED,
                                          __HIP_MEMORY_SCOPE_AGENT);
            }
            if (f == 2) break;               // inclusive prefix absorbed
            --p;
        }
        if (lane < N_EXP)
            __hip_atomic_store(&incl[c * N_EXP + lane], base + cnt,
                               __ATOMIC_RELAXED, __HIP_MEMORY_SCOPE_AGENT);
        __hip_atomic_store(&flag[c], 2, __ATOMIC_RELEASE,
                           __HIP_MEMORY_SCOPE_AGENT);
    }

    if (c == N_CHUNK - 1 && lane < N_EXP)
        count[lane] = base + cnt;            // grand totals

    // ---- pos / keep / slot_map ----
    const int base_e = __shfl(base, e);      // expert e's base lives in lane e
    const int pos = base_e + rank;
    pos_f[t]  = (float)pos;
    keep_f[t] = (pos < CAP) ? 1.0f : 0.0f;
    if (pos < CAP) slot_map[e * CAP + pos] = t;
}

// ---------------------------------------------------------------------------
// K2: pure streaming fill. One block per output row; copy or zero.
// Slots [0, count[e]) are dense-filled this call, so slot_map is never read
// stale on the taken path; count/slot_map loads issue in parallel (both
// wave-uniform -> scalar loads).
// ---------------------------------------------------------------------------
__global__ void __launch_bounds__(256)
k_fill(const float* __restrict__ inputs,
       const int* __restrict__ slot_map,
       const int* __restrict__ count,
       float* __restrict__ dispatched) {
    const int s   = blockIdx.x;              // e*CAP + c
    const int e   = s >> 11;
    const int c   = s & (CAP - 1);
    const int tid = threadIdx.x;
    const int cnte = count[e];               // parallel scalar loads
    const int tok  = slot_map[s];
    float4* out4 = (float4*)(dispatched + (size_t)s * DMODEL);
    if (c < cnte) {
        const float4* in4 =
            (const float4*)(inputs + (size_t)(tok & (N_TOK - 1)) * DMODEL);
        out4[tid]       = in4[tid];
        out4[tid + 256] = in4[tid + 256];
    } else {
        const float4 z = {0.f, 0.f, 0.f, 0.f};
        out4[tid]       = z;
        out4[tid + 256] = z;
    }
}

// ---------------------------------------------------------------------------
extern "C" void kernel_launch(void* const* d_in, const int* in_sizes, int n_in,
                              void* d_out, int out_size, void* d_ws, size_t ws_size,
                              hipStream_t stream) {
    const float* inputs = (const float*)d_in[0];
    const float* score  = (const float*)d_in[1];

    float* out        = (float*)d_out;
    float* dispatched = out;                                   // E*CAP*DMODEL
    float* expert_f   = out + (size_t)N_EXP * CAP * DMODEL;    // N_TOK
    float* pos_f      = expert_f + N_TOK;                      // N_TOK
    float* keep_f     = pos_f + N_TOK;                         // N_TOK

    int* slot_map = (int*)d_ws;                    // N_EXP * CAP
    int* count    = slot_map + N_EXP * CAP;        // N_EXP
    int* agg      = count + N_EXP;                 // N_CHUNK * N_EXP
    int* incl     = agg + N_CHUNK * N_EXP;         // N_CHUNK * N_EXP
    int* flag     = incl + N_CHUNK * N_EXP;        // N_CHUNK

    // lookback flags must start at 0 every call (tiny: 1 KB)
    hipMemsetAsync(flag, 0, N_CHUNK * sizeof(int), stream);

    k_route<<<N_CHUNK, CHUNK, 0, stream>>>(score, expert_f, pos_f, keep_f,
                                           slot_map, count, agg, incl, flag);
    k_fill<<<N_EXP * CAP, 256, 0, stream>>>(inputs, slot_map, count, dispatched);
}

// Round 5
// 91.524 us; speedup vs baseline: 1.5746x; 1.5746x over previous
//
#include <hip/hip_runtime.h>

#define N_TOK   16384
#define DMODEL  2048
#define N_EXP   16
#define CAP     2048             // 2 * N_TOK / N_EXP
#define CHUNK   256              // one block per chunk
#define N_CHUNK (N_TOK / CHUNK)  // 64

// ---------------------------------------------------------------------------
// K1: per-token argmax (first-max semantics) + per-chunk expert histogram +
// in-chunk rank (order-preserving). 64 blocks x 256 threads.
// rank[t] = # tokens in this chunk before t with the same expert.
// ---------------------------------------------------------------------------
__global__ void __launch_bounds__(256)
k_hist(const float* __restrict__ score,
       int* __restrict__ eidx,
       int* __restrict__ rank,
       float* __restrict__ expert_f,
       int* __restrict__ hist) {
    const int tid  = threadIdx.x;
    const int c    = blockIdx.x;
    const int t    = c * CHUNK + tid;
    const int wave = tid >> 6;
    const int lane = tid & 63;

    const float4* s4 = (const float4*)(score + (size_t)t * N_EXP);
    float4 a = s4[0], b = s4[1], cc = s4[2], d = s4[3];
    float v[16] = {a.x,a.y,a.z,a.w, b.x,b.y,b.z,b.w,
                   cc.x,cc.y,cc.z,cc.w, d.x,d.y,d.z,d.w};
    float best = v[0];
    int e = 0;
#pragma unroll
    for (int j = 1; j < 16; ++j)
        if (v[j] > best) { best = v[j]; e = j; }   // strict > keeps first max

    eidx[t] = e;
    expert_f[t] = (float)e;

    // per-wave ballots: in-wave rank + per-wave per-expert counts
    __shared__ int wh[4][N_EXP];
    const unsigned long long below = (1ull << lane) - 1ull;
    int rw = 0;
#pragma unroll
    for (int ex = 0; ex < N_EXP; ++ex) {
        unsigned long long m = __ballot(e == ex);
        if (e == ex) rw = __popcll(m & below);
        if (lane == 0) wh[wave][ex] = __popcll(m);
    }
    __syncthreads();

    int r = rw;
#pragma unroll
    for (int w = 0; w < 4; ++w)
        if (w < wave) r += wh[w][e];
    rank[t] = r;

    if (tid < N_EXP)
        hist[c * N_EXP + tid] = wh[0][tid] + wh[1][tid] + wh[2][tid] + wh[3][tid];
}

// ---------------------------------------------------------------------------
// K2: per-block redundant exclusive scan over the 4KB L2-hot hist, then pure
// elementwise pos/keep/slot_map writes. 64 blocks x 256 threads.
// Thread layout for scan: eg = tid&15 (expert), g = tid>>4 (group of chunks).
// ---------------------------------------------------------------------------
__global__ void __launch_bounds__(256)
k_pos(const int* __restrict__ eidx,
      const int* __restrict__ rank,
      const int* __restrict__ hist,
      int* __restrict__ slot_map,
      int* __restrict__ count,
      float* __restrict__ pos_f,
      float* __restrict__ keep_f) {
    const int tid = threadIdx.x;
    const int c   = blockIdx.x;

    __shared__ int part[16][17];   // [group][expert] (+1 pad)
    __shared__ int base_e[N_EXP];

    const int eg = tid & 15;
    const int g  = tid >> 4;       // 16 groups, each covers 4 chunks
    int p = 0;
#pragma unroll
    for (int i = 0; i < 4; ++i) {
        const int k = g + 16 * i;
        if (k < c) p += hist[k * N_EXP + eg];
    }
    part[g][eg] = p;
    __syncthreads();
    if (tid < N_EXP) {
        int s = 0;
#pragma unroll
        for (int gg = 0; gg < 16; ++gg) s += part[gg][tid];
        base_e[tid] = s;
        if (c == N_CHUNK - 1)
            count[tid] = s + hist[(N_CHUNK - 1) * N_EXP + tid];
    }
    __syncthreads();

    const int t   = c * CHUNK + tid;
    const int e   = eidx[t];
    const int pos = base_e[e] + rank[t];
    pos_f[t]  = (float)pos;
    keep_f[t] = (pos < CAP) ? 1.0f : 0.0f;
    if (pos < CAP) slot_map[e * CAP + pos] = t;
}

// ---------------------------------------------------------------------------
// K3: pure streaming fill. One block per output row; copy or zero.
// Slots [0, min(count[e],CAP)) are dense-filled this call, so slot_map is
// never read stale on the taken path.
// ---------------------------------------------------------------------------
__global__ void __launch_bounds__(256)
k_fill(const float* __restrict__ inputs,
       const int* __restrict__ slot_map,
       const int* __restrict__ count,
       float* __restrict__ dispatched) {
    const int s   = blockIdx.x;              // e*CAP + c
    const int e   = s >> 11;
    const int c   = s & (CAP - 1);
    const int tid = threadIdx.x;
    const int cnte = count[e];               // scalar loads, issue in parallel
    const int tok  = slot_map[s];
    float4* out4 = (float4*)(dispatched + (size_t)s * DMODEL);
    if (c < cnte) {
        const float4* in4 =
            (const float4*)(inputs + (size_t)(tok & (N_TOK - 1)) * DMODEL);
        out4[tid]       = in4[tid];
        out4[tid + 256] = in4[tid + 256];
    } else {
        const float4 z = {0.f, 0.f, 0.f, 0.f};
        out4[tid]       = z;
        out4[tid + 256] = z;
    }
}

// ---------------------------------------------------------------------------
extern "C" void kernel_launch(void* const* d_in, const int* in_sizes, int n_in,
                              void* d_out, int out_size, void* d_ws, size_t ws_size,
                              hipStream_t stream) {
    const float* inputs = (const float*)d_in[0];
    const float* score  = (const float*)d_in[1];

    float* out        = (float*)d_out;
    float* dispatched = out;                                   // E*CAP*DMODEL
    float* expert_f   = out + (size_t)N_EXP * CAP * DMODEL;    // N_TOK
    float* pos_f      = expert_f + N_TOK;                      // N_TOK
    float* keep_f     = pos_f + N_TOK;                         // N_TOK

    int* eidx     = (int*)d_ws;                    // N_TOK
    int* rank     = eidx + N_TOK;                  // N_TOK
    int* hist     = rank + N_TOK;                  // N_CHUNK * N_EXP
    int* slot_map = hist + N_CHUNK * N_EXP;        // N_EXP * CAP
    int* count    = slot_map + N_EXP * CAP;        // N_EXP

    k_hist<<<N_CHUNK, CHUNK, 0, stream>>>(score, eidx, rank, expert_f, hist);
    k_pos<<<N_CHUNK, CHUNK, 0, stream>>>(eidx, rank, hist, slot_map, count,
                                         pos_f, keep_f);
    k_fill<<<N_EXP * CAP, 256, 0, stream>>>(inputs, slot_map, count, dispatched);
}

// Round 7
// 65.679 us; speedup vs baseline: 2.1943x; 1.3935x over previous
//
#include <hip/hip_runtime.h>

#define N_TOK   16384
#define DMODEL  2048
#define N_EXP   16
#define CAP     2048             // 2 * N_TOK / N_EXP
#define CHUNK   256              // one block per chunk
#define N_CHUNK (N_TOK / CHUNK)  // 64

typedef float f4 __attribute__((ext_vector_type(4)));  // NT builtin needs this

// ---------------------------------------------------------------------------
// K1: per-token argmax (first-max semantics) + per-chunk expert histogram +
// in-chunk rank (order-preserving). 64 blocks x 256 threads.
// ---------------------------------------------------------------------------
__global__ void __launch_bounds__(256)
k_hist(const float* __restrict__ score,
       int* __restrict__ eidx,
       int* __restrict__ rank,
       float* __restrict__ expert_f,
       int* __restrict__ hist) {
    const int tid  = threadIdx.x;
    const int c    = blockIdx.x;
    const int t    = c * CHUNK + tid;
    const int wave = tid >> 6;
    const int lane = tid & 63;

    const float4* s4 = (const float4*)(score + (size_t)t * N_EXP);
    float4 a = s4[0], b = s4[1], cc = s4[2], d = s4[3];
    float v[16] = {a.x,a.y,a.z,a.w, b.x,b.y,b.z,b.w,
                   cc.x,cc.y,cc.z,cc.w, d.x,d.y,d.z,d.w};
    float best = v[0];
    int e = 0;
#pragma unroll
    for (int j = 1; j < 16; ++j)
        if (v[j] > best) { best = v[j]; e = j; }   // strict > keeps first max

    eidx[t] = e;
    expert_f[t] = (float)e;

    __shared__ int wh[4][N_EXP];
    const unsigned long long below = (1ull << lane) - 1ull;
    int rw = 0;
#pragma unroll
    for (int ex = 0; ex < N_EXP; ++ex) {
        unsigned long long m = __ballot(e == ex);
        if (e == ex) rw = __popcll(m & below);
        if (lane == 0) wh[wave][ex] = __popcll(m);
    }
    __syncthreads();

    int r = rw;
#pragma unroll
    for (int w = 0; w < 4; ++w)
        if (w < wave) r += wh[w][e];
    rank[t] = r;

    if (tid < N_EXP)
        hist[c * N_EXP + tid] = wh[0][tid] + wh[1][tid] + wh[2][tid] + wh[3][tid];
}

// ---------------------------------------------------------------------------
// K2: per-block redundant exclusive scan over the 4KB L2-hot hist, then pure
// elementwise pos/keep/slot_map writes. 64 blocks x 256 threads.
// ---------------------------------------------------------------------------
__global__ void __launch_bounds__(256)
k_pos(const int* __restrict__ eidx,
      const int* __restrict__ rank,
      const int* __restrict__ hist,
      int* __restrict__ slot_map,
      int* __restrict__ count,
      float* __restrict__ pos_f,
      float* __restrict__ keep_f) {
    const int tid = threadIdx.x;
    const int c   = blockIdx.x;

    __shared__ int part[16][17];   // [group][expert] (+1 pad)
    __shared__ int base_e[N_EXP];

    const int eg = tid & 15;
    const int g  = tid >> 4;       // 16 groups, each covers 4 chunks
    int p = 0;
#pragma unroll
    for (int i = 0; i < 4; ++i) {
        const int k = g + 16 * i;
        if (k < c) p += hist[k * N_EXP + eg];
    }
    part[g][eg] = p;
    __syncthreads();
    if (tid < N_EXP) {
        int s = 0;
#pragma unroll
        for (int gg = 0; gg < 16; ++gg) s += part[gg][tid];
        base_e[tid] = s;
        if (c == N_CHUNK - 1)
            count[tid] = s + hist[(N_CHUNK - 1) * N_EXP + tid];
    }
    __syncthreads();

    const int t   = c * CHUNK + tid;
    const int e   = eidx[t];
    const int pos = base_e[e] + rank[t];
    pos_f[t]  = (float)pos;
    keep_f[t] = (pos < CAP) ? 1.0f : 0.0f;
    if (pos < CAP) slot_map[e * CAP + pos] = t;
}

// ---------------------------------------------------------------------------
// K3: pure streaming fill with NONTEMPORAL stores. The 256 MiB output is
// write-once / never-read-in-kernel: bypassing the cache hierarchy on the
// write stream keeps the static 128 MiB `inputs` resident in the 256 MiB
// Infinity Cache across graph replays, turning reads into L3 hits.
// ---------------------------------------------------------------------------
__global__ void __launch_bounds__(256)
k_fill(const float* __restrict__ inputs,
       const int* __restrict__ slot_map,
       const int* __restrict__ count,
       float* __restrict__ dispatched) {
    const int s   = blockIdx.x;              // e*CAP + c
    const int e   = s >> 11;
    const int c   = s & (CAP - 1);
    const int tid = threadIdx.x;
    const int cnte = count[e];               // scalar loads, issue in parallel
    const int tok  = slot_map[s];
    f4* out4 = (f4*)(dispatched + (size_t)s * DMODEL);
    if (c < cnte) {
        const f4* in4 =
            (const f4*)(inputs + (size_t)(tok & (N_TOK - 1)) * DMODEL);
        f4 x0 = in4[tid];
        f4 x1 = in4[tid + 256];
        __builtin_nontemporal_store(x0, &out4[tid]);
        __builtin_nontemporal_store(x1, &out4[tid + 256]);
    } else {
        const f4 z = {0.f, 0.f, 0.f, 0.f};
        __builtin_nontemporal_store(z, &out4[tid]);
        __builtin_nontemporal_store(z, &out4[tid + 256]);
    }
}

// ---------------------------------------------------------------------------
extern "C" void kernel_launch(void* const* d_in, const int* in_sizes, int n_in,
                              void* d_out, int out_size, void* d_ws, size_t ws_size,
                              hipStream_t stream) {
    const float* inputs = (const float*)d_in[0];
    const float* score  = (const float*)d_in[1];

    float* out        = (float*)d_out;
    float* dispatched = out;                                   // E*CAP*DMODEL
    float* expert_f   = out + (size_t)N_EXP * CAP * DMODEL;    // N_TOK
    float* pos_f      = expert_f + N_TOK;                      // N_TOK
    float* keep_f     = pos_f + N_TOK;                         // N_TOK

    int* eidx     = (int*)d_ws;                    // N_TOK
    int* rank     = eidx + N_TOK;                  // N_TOK
    int* hist     = rank + N_TOK;                  // N_CHUNK * N_EXP
    int* slot_map = hist + N_CHUNK * N_EXP;        // N_EXP * CAP
    int* count    = slot_map + N_EXP * CAP;        // N_EXP

    k_hist<<<N_CHUNK, CHUNK, 0, stream>>>(score, eidx, rank, expert_f, hist);
    k_pos<<<N_CHUNK, CHUNK, 0, stream>>>(eidx, rank, hist, slot_map, count,
                                         pos_f, keep_f);
    k_fill<<<N_EXP * CAP, 256, 0, stream>>>(inputs, slot_map, count, dispatched);
}